// Round 7
// baseline (141.753 us; speedup 1.0000x reference)
//
#include <hip/hip_runtime.h>

// WaveletLayer: db2 DWT -> gain -> IDWT -> ReLU fused as one 6-tap stencil.
// PERSISTENT grid-stride streamer: 2048 blocks x 256 threads (8 blocks/CU
// resident), each thread processes 4 tasks of 8 outputs with a depth-2
// software pipeline (next batch's 9 loads issued before current compute) so
// memory queues stay continuously full -- no wave churn, no barriers.
// Per task: 2 aligned float4 x-loads + 2 float2 halos (1.5x amp, L1 dedupes)
// + 5 scalar gains, 2 float4 stores. B=4096 rows, N=4096, L=2049.

#define NN 4096
#define LL 2049
#define OCTS 512          // 8-output tasks per row
#define NBLK 2048
#define NTHR 256
#define STRIDE (NBLK * NTHR)                    // 524288 threads
#define ITERS ((4096 * OCTS) / STRIDE)          // 4 tasks per thread

struct Batch {
    float4 c0, c1;
    float2 hl, hr;
    float g0, g1, g2, g3, g4;
};

__device__ __forceinline__ void load_batch(Batch& b, const float* __restrict__ x,
                                           const float* __restrict__ ker, int tau) {
    const int row  = tau >> 9;          // OCTS = 512
    const int u    = tau & (OCTS - 1);
    const int base = 8 * u;
    const float* xrow = x + (size_t)row * NN;
    const bool first = (u == 0);
    const bool last  = (u == OCTS - 1);
    const int la = first ? 0 : (base - 2);
    const int ra = last ? (NN - 2) : (base + 8);
    b.c0 = *(const float4*)(xrow + base);
    b.c1 = *(const float4*)(xrow + base + 4);
    b.hl = *(const float2*)(xrow + la);
    b.hr = *(const float2*)(xrow + ra);
    const float* krow = ker + (size_t)row * LL + 4 * u;
    b.g0 = krow[0]; b.g1 = krow[1]; b.g2 = krow[2]; b.g3 = krow[3]; b.g4 = krow[4];
}

__device__ __forceinline__ void process(const Batch& b, float* __restrict__ out, int tau) {
    const float lo0 = -0.12940952255126037f, lo1 = 0.22414386804185735f,
                lo2 =  0.8365163037378079f,  lo3 = 0.48296291314453416f;
    const float hi0 = -0.48296291314453416f, hi1 = 0.8365163037378079f,
                hi2 = -0.22414386804185735f, hi3 = -0.12940952255126037f;

    const int row  = tau >> 9;
    const int u    = tau & (OCTS - 1);
    const bool first = (u == 0);
    const bool last  = (u == OCTS - 1);

    float E[12];
    E[0] = first ? b.hl.y : b.hl.x;   // X(base-2)  [X(-2)=x[1]]
    E[1] = first ? b.hl.x : b.hl.y;   // X(base-1)  [X(-1)=x[0]]
    E[2] = b.c0.x; E[3] = b.c0.y; E[4] = b.c0.z; E[5] = b.c0.w;
    E[6] = b.c1.x; E[7] = b.c1.y; E[8] = b.c1.z; E[9] = b.c1.w;
    E[10] = last ? b.hr.y : b.hr.x;   // X(base+8)  [X(4096)=x[4095]]
    E[11] = last ? b.hr.x : b.hr.y;   // X(base+9)  [X(4097)=x[4094]]

    const float g[5] = { b.g0, b.g1, b.g2, b.g3, b.g4 };
    float A[5], D[5];
    #pragma unroll
    for (int i = 0; i < 5; ++i) {
        const float e0 = E[2 * i], e1 = E[2 * i + 1];
        const float e2 = E[2 * i + 2], e3 = E[2 * i + 3];
        const float cA = lo3 * e0 + lo2 * e1 + lo1 * e2 + lo0 * e3;
        const float cD = hi3 * e0 + hi2 * e1 + hi1 * e2 + hi0 * e3;
        A[i] = g[i] * cA;
        D[i] = g[i] * cD;
    }

    float y[8];
    #pragma unroll
    for (int i = 0; i < 4; ++i) {
        float ye = lo1 * A[i] + lo3 * A[i + 1] + hi1 * D[i] + hi3 * D[i + 1];
        float yo = lo0 * A[i] + lo2 * A[i + 1] + hi0 * D[i] + hi2 * D[i + 1];
        y[2 * i]     = fmaxf(ye, 0.0f);
        y[2 * i + 1] = fmaxf(yo, 0.0f);
    }

    float* orow = out + (size_t)row * NN + 8 * u;
    *(float4*)(orow)     = make_float4(y[0], y[1], y[2], y[3]);
    *(float4*)(orow + 4) = make_float4(y[4], y[5], y[6], y[7]);
}

__global__ __launch_bounds__(NTHR) void wavelet_fused(const float* __restrict__ x,
                                                      const float* __restrict__ ker,
                                                      float* __restrict__ out) {
    const int tid = blockIdx.x * NTHR + threadIdx.x;

    Batch cur, nxt;
    load_batch(cur, x, ker, tid);
    #pragma unroll
    for (int k = 0; k < ITERS; ++k) {
        if (k + 1 < ITERS) load_batch(nxt, x, ker, tid + (k + 1) * STRIDE);
        process(cur, out, tid + k * STRIDE);
        cur = nxt;
    }
}

extern "C" void kernel_launch(void* const* d_in, const int* in_sizes, int n_in,
                              void* d_out, int out_size, void* d_ws, size_t ws_size,
                              hipStream_t stream) {
    const float* x   = (const float*)d_in[0];
    const float* ker = (const float*)d_in[1];
    float* out = (float*)d_out;
    wavelet_fused<<<dim3(NBLK), dim3(NTHR), 0, stream>>>(x, ker, out);
}